// Round 1
// baseline (299.982 us; speedup 1.0000x reference)
//
#include <hip/hip_runtime.h>
#include <hip/hip_bf16.h>
#include <cstdint>

typedef __bf16 bf16x8 __attribute__((ext_vector_type(8)));
typedef float f32x4 __attribute__((ext_vector_type(4)));

#define M_DIM 8192
#define H_DIM 1024
#define K_DIM 2048
#define NKT 32   // K tiles of 64

__device__ __forceinline__ void async_copy16(void* lds, const void* g) {
    __builtin_amdgcn_global_load_lds(
        (const __attribute__((address_space(1))) uint32_t*)g,
        (__attribute__((address_space(3))) uint32_t*)lds, 16, 0, 0);
}

__device__ __forceinline__ float fast_sigmoid(float x) {
    return __builtin_amdgcn_rcpf(1.0f + __expf(-x));
}
__device__ __forceinline__ float fast_tanh(float x) {
    float t = __expf(-2.0f * x);
    return (1.0f - t) * __builtin_amdgcn_rcpf(1.0f + t);
}

// ---- pack A = bf16([x|h]), row-major [8192][2048], XOR-swizzled ----
// Logical 16B-chunk c of row r stored at chunk pos (c&~7)|((c&7)^(r&7)).
__global__ __launch_bounds__(256) void pack_a(
    const float* __restrict__ x, const float* __restrict__ h,
    __bf16* __restrict__ A) {
    const int ab = blockIdx.x;          // 4 batch rows per block
    const int t = threadIdx.x;
    #pragma unroll
    for (int i = 0; i < 4; ++i) {
        int p = t + i * 256;            // 0..1023
        int row = ab * 4 + (p >> 8);
        int c = p & 255;
        int col = c * 8;
        const float* src = (col < 1024) ? x + (size_t)row * 1024 + col
                                        : h + (size_t)row * 1024 + (col - 1024);
        float4 v0 = ((const float4*)src)[0];
        float4 v1 = ((const float4*)src)[1];
        union { __bf16 bb[8]; uint4 u; } pk;
        pk.bb[0] = (__bf16)v0.x; pk.bb[1] = (__bf16)v0.y;
        pk.bb[2] = (__bf16)v0.z; pk.bb[3] = (__bf16)v0.w;
        pk.bb[4] = (__bf16)v1.x; pk.bb[5] = (__bf16)v1.y;
        pk.bb[6] = (__bf16)v1.z; pk.bb[7] = (__bf16)v1.w;
        int sw = (c & ~7) | ((c & 7) ^ (row & 7));
        *(uint4*)(A + (size_t)row * K_DIM + sw * 8) = pk.u;
    }
}

// ---- pack Bt[n'][k] = bf16(W^T), gate-interleaved rows, XOR-swizzled ----
// Global gate column n_g = g*1024 + j  ->  row n' = (j>>4)*64 + g*16 + (j&15).
// Within each 256-row N-tile, a wave's four 16-row fragments are the 4 gates
// of the same 16 j-columns (lane-local LSTM epilogue).
// Note (n'&7) == (j&7), so the per-row chunk swizzle uses n'&7.
__global__ __launch_bounds__(256) void pack_bt(
    const float* __restrict__ Wx, const float* __restrict__ Wh,
    __bf16* __restrict__ Bt) {
    __shared__ float tile[64 * 65];
    const int b = blockIdx.x;
    const int t = threadIdx.x;
    const int bn = b & 63;
    const int bk = b >> 6;
    const int n0 = bn * 64, k0 = bk * 64;
    const float* W = (k0 < 1024) ? Wx + (size_t)k0 * 4096
                                 : Wh + (size_t)(k0 - 1024) * 4096;
    #pragma unroll
    for (int i = 0; i < 4; ++i) {
        int p = t + i * 256;
        int kr = p >> 4, c4 = p & 15;
        float4 v = *(const float4*)(W + (size_t)kr * 4096 + n0 + c4 * 4);
        float* dst = tile + kr * 65 + c4 * 4;
        dst[0] = v.x; dst[1] = v.y; dst[2] = v.z; dst[3] = v.w;
    }
    __syncthreads();
    #pragma unroll
    for (int i = 0; i < 2; ++i) {
        int p = t + i * 256;
        int n = p >> 3, ch = p & 7;
        int ng = n0 + n;                       // global gate-column 0..4095
        union { __bf16 bb[8]; uint4 u; } pk;
        #pragma unroll
        for (int j2 = 0; j2 < 8; ++j2)
            pk.bb[j2] = (__bf16)tile[(ch * 8 + j2) * 65 + n];
        int g = ng >> 10;
        int j = ng & 1023;
        int np = ((j >> 4) << 6) | (g << 4) | (j & 15);   // interleaved row
        int c = (k0 >> 3) + ch;
        int sw = (c & ~7) | ((c & 7) ^ (np & 7));
        *(uint4*)(Bt + (size_t)np * K_DIM + sw * 8) = pk.u;
    }
}

// ============================================================================
// 256x256-tile, BK=64, 8-wave (2Mx4N), 8-phase schedule with counted vmcnt.
// LDS: 2 buffers x (A 256x64 | B 256x64) bf16 = 128 KiB.
// A region layout per buf: [qm][128 rows][64 k] where region qm holds tile
//   rows {qm*64..qm*64+63} U {128+qm*64..128+qm*64+63} (the rows read by
//   quadrant qm of both M-waves) -> each 16KB region becomes read-dead after
//   its last quadrant phase, so restaging it is WAR-safe.
// B region layout per buf: [qn][128 rows][64 k], region qn holds n'-rows
//   {wn*64+qn*32..+31 : wn=0..3}.
// Per K-tile: 4 phases = quadrants (0,0),(0,1),(1,1),(1,0); each phase:
//   ds-reads -> barrier -> lgkmcnt(0) -> setprio(1) 16xMFMA setprio(0)
//   -> stage issues (region just gone read-dead) -> [vmcnt(8) at P4] -> barrier
// Stage targets tile t+2 into the SAME buffer being computed (parity t&1).
// vmcnt(8) at each P4 leaves exactly this group's 8 issues in flight and
// confirms the previous group's 8 (= next tile's data). Never drains to 0
// until the last two groups.
// ============================================================================
__global__ __launch_bounds__(512, 2) void lstm_gemm(
    const __bf16* __restrict__ A, const __bf16* __restrict__ Bt,
    const float* __restrict__ bx, const float* __restrict__ cin,
    float* __restrict__ out) {
    __shared__ __bf16 lds[2][32768];   // 128 KiB

    const int tid = threadIdx.x;
    const int lane = tid & 63;
    const int wid = tid >> 6;
    const int wm = wid >> 2;           // 0..1
    const int wn = wid & 3;            // 0..3
    const int lm = lane & 15, lu = lane >> 4;

    // XCD-aware swizzle: 512 blocks, 8 XCDs; XCD x owns by in {2x,2x+1}
    // (2 x 1MB Bt panels, L2-resident), bx streams over all 32 M-panels.
    const int b = blockIdx.x;
    const int xcd = b & 7, cc = b >> 3;
    const int by = xcd * 2 + (cc >> 5);     // 0..15  (N'/256)
    const int bxc = cc & 31;                // 0..31  (M/256)
    const int bm0 = bxc * 256;
    const int nb0 = by * 256;

    // ---- staging base pointers (per thread) ----
    const int lr = tid >> 3;           // 0..63 (row in round 0)
    const int ch = tid & 7;
    const __bf16* pA = A + (size_t)(bm0 + lr) * K_DIM + ch * 8;
    const __bf16* pB = Bt + (size_t)(nb0 + ((lr >> 5) << 6) + (lr & 31)) * K_DIM + ch * 8;
    // const element offsets: A half qm: +qm*131072 ; round1: +262144 ; +kt*64
    //                        B half qn: +qn*65536  ; round1: +262144 ; +kt*64

#define STAGE_A(P, QM, KT) do { \
    async_copy16(&lds[P][((QM) << 13) + tid * 8],        pA + (QM) * 131072 + (KT) * 64); \
    async_copy16(&lds[P][((QM) << 13) + 4096 + tid * 8], pA + (QM) * 131072 + 262144 + (KT) * 64); \
} while (0)
#define STAGE_B(P, QN, KT) do { \
    async_copy16(&lds[P][16384 + ((QN) << 13) + tid * 8],        pB + (QN) * 65536 + (KT) * 64); \
    async_copy16(&lds[P][16384 + ((QN) << 13) + 4096 + tid * 8], pB + (QN) * 65536 + 262144 + (KT) * 64); \
} while (0)

    // ---- prologue: stage tile 0 -> buf0, tile 1 -> buf1 (order pinned) ----
    STAGE_A(0, 0, 0); STAGE_A(0, 1, 0); STAGE_B(0, 0, 0); STAGE_B(0, 1, 0);
    __builtin_amdgcn_sched_barrier(0);
    STAGE_A(1, 0, 1); STAGE_A(1, 1, 1); STAGE_B(1, 0, 1); STAGE_B(1, 1, 1);
    __builtin_amdgcn_sched_barrier(0);

    // swizzled k-chunk byte offsets for ds_read_b128 (row parity = lm&7)
    const int jo0 = ((0 + lu) ^ (lm & 7)) * 8;   // kk=0, elements
    const int jo1 = ((4 + lu) ^ (lm & 7)) * 8;   // kk=1

    f32x4 acc[2][2][4][2];
    #pragma unroll
    for (int i0 = 0; i0 < 2; ++i0)
        #pragma unroll
        for (int k0_ = 0; k0_ < 2; ++k0_)
            #pragma unroll
            for (int m0 = 0; m0 < 4; ++m0)
                #pragma unroll
                for (int n0_ = 0; n0_ < 2; ++n0_)
                    acc[i0][k0_][m0][n0_] = f32x4{0.f, 0.f, 0.f, 0.f};

    bf16x8 a_[4][2];
    bf16x8 b_[2][2];

    asm volatile("s_waitcnt vmcnt(8)" ::: "memory");   // tile 0 resident
    __builtin_amdgcn_s_barrier();

#define READ_A(P, QM) do { \
    _Pragma("unroll") \
    for (int m_ = 0; m_ < 4; ++m_) { \
        const __bf16* ba_ = &lds[P][((QM) << 13) + (wm * 64 + m_ * 16 + lm) * 64]; \
        a_[m_][0] = *(const bf16x8*)(ba_ + jo0); \
        a_[m_][1] = *(const bf16x8*)(ba_ + jo1); \
    } \
} while (0)
#define READ_B(P, QN) do { \
    _Pragma("unroll") \
    for (int n_ = 0; n_ < 2; ++n_) { \
        const __bf16* bb_ = &lds[P][16384 + ((QN) << 13) + (wn * 32 + n_ * 16 + lm) * 64]; \
        b_[n_][0] = *(const bf16x8*)(bb_ + jo0); \
        b_[n_][1] = *(const bf16x8*)(bb_ + jo1); \
    } \
} while (0)
#define MFMA_PH(QM, QN) \
    _Pragma("unroll") \
    for (int m_ = 0; m_ < 4; ++m_) { \
        _Pragma("unroll") \
        for (int n_ = 0; n_ < 2; ++n_) { \
            acc[QM][QN][m_][n_] = __builtin_amdgcn_mfma_f32_16x16x32_bf16( \
                a_[m_][0], b_[n_][0], acc[QM][QN][m_][n_], 0, 0, 0); \
            acc[QM][QN][m_][n_] = __builtin_amdgcn_mfma_f32_16x16x32_bf16( \
                a_[m_][1], b_[n_][1], acc[QM][QN][m_][n_], 0, 0, 0); \
        } \
    }
#define PH_PRE() \
    __builtin_amdgcn_sched_barrier(0); \
    __builtin_amdgcn_s_barrier(); \
    asm volatile("s_waitcnt lgkmcnt(0)" ::: "memory"); \
    __builtin_amdgcn_sched_barrier(0); \
    __builtin_amdgcn_s_setprio(1)
#define PH_END() \
    __builtin_amdgcn_sched_barrier(0); \
    __builtin_amdgcn_s_barrier()

#define GROUP(P, T) do { \
    const int kt2_ = (T) + 2; \
    const bool st_ = kt2_ < NKT; \
    /* P1 quadrant (0,0): read A-qm0 (8) + B-qn0 (4) */ \
    READ_A(P, 0); READ_B(P, 0); \
    PH_PRE(); MFMA_PH(0, 0); __builtin_amdgcn_s_setprio(0); \
    PH_END(); \
    /* P2 quadrant (0,1): read B-qn1 (4), reuse A-qm0; A-qm0 now read-dead */ \
    READ_B(P, 1); \
    PH_PRE(); MFMA_PH(0, 1); __builtin_amdgcn_s_setprio(0); \
    if (st_) STAGE_A(P, 0, kt2_); \
    PH_END(); \
    /* P3 quadrant (1,1): read A-qm1 (8), reuse B-qn1; B-qn1 now read-dead */ \
    READ_A(P, 1); \
    PH_PRE(); MFMA_PH(1, 1); __builtin_amdgcn_s_setprio(0); \
    if (st_) STAGE_B(P, 1, kt2_); \
    PH_END(); \
    /* P4 quadrant (1,0): re-read B-qn0 (4); A-qm1 + B-qn0 read-dead after */ \
    READ_B(P, 0); \
    PH_PRE(); MFMA_PH(1, 0); __builtin_amdgcn_s_setprio(0); \
    if (st_) { STAGE_A(P, 1, kt2_); STAGE_B(P, 0, kt2_); } \
    if ((T) < NKT - 2) asm volatile("s_waitcnt vmcnt(8)" ::: "memory"); \
    else               asm volatile("s_waitcnt vmcnt(0)" ::: "memory"); \
    PH_END(); \
} while (0)

    #pragma unroll 1
    for (int it = 0; it < NKT / 2; ++it) {
        GROUP(0, 2 * it);
        GROUP(1, 2 * it + 1);
    }

    // ---- LSTM epilogue: gate = qn*2+nf is lane-local ----
    const int j = (by * 4 + wn) * 16 + lm;
    const float bi  = bx[j];
    const float bff = bx[H_DIM + j];
    const float bg  = bx[2 * H_DIM + j];
    const float bo  = bx[3 * H_DIM + j];
    #pragma unroll
    for (int qm = 0; qm < 2; ++qm) {
        #pragma unroll
        for (int m = 0; m < 4; ++m) {
            const int row0 = bm0 + wm * 128 + qm * 64 + m * 16 + lu * 4;
            #pragma unroll
            for (int r = 0; r < 4; ++r) {
                const size_t off = (size_t)(row0 + r) * H_DIM + j;
                const float iv = fast_sigmoid(acc[qm][0][m][0][r] + bi);
                const float fv = fast_sigmoid(acc[qm][0][m][1][r] + bff);
                const float gv = fast_tanh(acc[qm][1][m][0][r] + bg);
                const float ov = fast_sigmoid(acc[qm][1][m][1][r] + bo);
                const float cn = fv * cin[off] + iv * gv;
                out[off] = ov * fast_tanh(cn);
                out[(size_t)M_DIM * H_DIM + off] = cn;
            }
        }
    }
#undef STAGE_A
#undef STAGE_B
#undef READ_A
#undef READ_B
#undef MFMA_PH
#undef PH_PRE
#undef PH_END
#undef GROUP
}

extern "C" void kernel_launch(void* const* d_in, const int* in_sizes, int n_in,
                              void* d_out, int out_size, void* d_ws, size_t ws_size,
                              hipStream_t stream) {
    const float* x  = (const float*)d_in[0];
    const float* h  = (const float*)d_in[1];
    const float* c  = (const float*)d_in[2];
    const float* Wx = (const float*)d_in[3];
    const float* bx = (const float*)d_in[4];
    const float* Wh = (const float*)d_in[5];
    float* out = (float*)d_out;

    __bf16* A  = (__bf16*)d_ws;                                      // 32 MB
    __bf16* Bt = (__bf16*)((char*)d_ws + (size_t)M_DIM * K_DIM * 2); // 16 MB

    pack_a<<<M_DIM / 4, 256, 0, stream>>>(x, h, A);
    pack_bt<<<2048, 256, 0, stream>>>(Wx, Wh, Bt);
    lstm_gemm<<<512, 512, 0, stream>>>(A, Bt, bx, c, out);
}

// Round 2
// 291.215 us; speedup vs baseline: 1.0301x; 1.0301x over previous
//
#include <hip/hip_runtime.h>
#include <hip/hip_bf16.h>
#include <cstdint>

typedef __bf16 bf16x8 __attribute__((ext_vector_type(8)));
typedef float f32x4 __attribute__((ext_vector_type(4)));

#define M_DIM 8192
#define H_DIM 1024
#define K_DIM 2048
#define NKT 32   // K tiles of 64

__device__ __forceinline__ void async_copy16(void* lds, const void* g) {
    __builtin_amdgcn_global_load_lds(
        (const __attribute__((address_space(1))) uint32_t*)g,
        (__attribute__((address_space(3))) uint32_t*)lds, 16, 0, 0);
}

__device__ __forceinline__ float fast_sigmoid(float x) {
    return __builtin_amdgcn_rcpf(1.0f + __expf(-x));
}
__device__ __forceinline__ float fast_tanh(float x) {
    float t = __expf(-2.0f * x);
    return (1.0f - t) * __builtin_amdgcn_rcpf(1.0f + t);
}

// ---- merged pack kernel: blocks [0,2048) pack A, [2048,4096) pack Bt ----
// A = bf16([x|h]) row-major [8192][2048], 16B-chunk c of row r stored at
// chunk pos (c&~7)|((c&7)^(r&7)).
// Bt[n'][k] = bf16(W^T), gate-interleaved rows: global gate col n_g=g*1024+j
// -> row n' = (j>>4)*64 + g*16 + (j&15); same chunk swizzle (n'&7 == j&7).
__global__ __launch_bounds__(256) void pack_ab(
    const float* __restrict__ x, const float* __restrict__ h,
    const float* __restrict__ Wx, const float* __restrict__ Wh,
    __bf16* __restrict__ A, __bf16* __restrict__ Bt) {
    __shared__ float tile[64 * 65];
    const int t = threadIdx.x;
    if (blockIdx.x < 2048) {
        const int ab = blockIdx.x;          // 4 batch rows per block
        #pragma unroll
        for (int i = 0; i < 4; ++i) {
            int p = t + i * 256;            // 0..1023
            int row = ab * 4 + (p >> 8);
            int c = p & 255;
            int col = c * 8;
            const float* src = (col < 1024) ? x + (size_t)row * 1024 + col
                                            : h + (size_t)row * 1024 + (col - 1024);
            float4 v0 = ((const float4*)src)[0];
            float4 v1 = ((const float4*)src)[1];
            union { __bf16 bb[8]; uint4 u; } pk;
            pk.bb[0] = (__bf16)v0.x; pk.bb[1] = (__bf16)v0.y;
            pk.bb[2] = (__bf16)v0.z; pk.bb[3] = (__bf16)v0.w;
            pk.bb[4] = (__bf16)v1.x; pk.bb[5] = (__bf16)v1.y;
            pk.bb[6] = (__bf16)v1.z; pk.bb[7] = (__bf16)v1.w;
            int sw = (c & ~7) | ((c & 7) ^ (row & 7));
            *(uint4*)(A + (size_t)row * K_DIM + sw * 8) = pk.u;
        }
    } else {
        const int b = blockIdx.x - 2048;
        const int bn = b & 63;
        const int bk = b >> 6;
        const int n0 = bn * 64, k0 = bk * 64;
        const float* W = (k0 < 1024) ? Wx + (size_t)k0 * 4096
                                     : Wh + (size_t)(k0 - 1024) * 4096;
        #pragma unroll
        for (int i = 0; i < 4; ++i) {
            int p = t + i * 256;
            int kr = p >> 4, c4 = p & 15;
            float4 v = *(const float4*)(W + (size_t)kr * 4096 + n0 + c4 * 4);
            float* dst = tile + kr * 65 + c4 * 4;
            dst[0] = v.x; dst[1] = v.y; dst[2] = v.z; dst[3] = v.w;
        }
        __syncthreads();
        #pragma unroll
        for (int i = 0; i < 2; ++i) {
            int p = t + i * 256;
            int n = p >> 3, ch = p & 7;
            int ng = n0 + n;                       // global gate-column 0..4095
            union { __bf16 bb[8]; uint4 u; } pk;
            #pragma unroll
            for (int j2 = 0; j2 < 8; ++j2)
                pk.bb[j2] = (__bf16)tile[(ch * 8 + j2) * 65 + n];
            int g = ng >> 10;
            int j = ng & 1023;
            int np = ((j >> 4) << 6) | (g << 4) | (j & 15);   // interleaved row
            int c = (k0 >> 3) + ch;
            int sw = (c & ~7) | ((c & 7) ^ (np & 7));
            *(uint4*)(Bt + (size_t)np * K_DIM + sw * 8) = pk.u;
        }
    }
}

// ============================================================================
// 256x256 tile, BK=64, 8 waves (2Mx4N), m201-faithful 4-phase/K-tile schedule.
// Per phase: [ds_reads + stage issues] -> barrier -> lgkmcnt(0) -> setprio(1)
// 16xMFMA setprio(0) -> barrier. Stages are co-issued with ds_reads in the
// pre-barrier block (fine interleave, m196's lever). A region is restaged one
// phase AFTER its last ds_read: the intervening barrier + per-wave lgkmcnt(0)
// drain makes the WAR safe for all waves.
// Stage plan for tile T (computing buf P=T&1):
//   P1(reads A0,B0): stage B0(T+1)->P^1   [B0(P^1) read-dead since T-1's P4]
//   P2(reads B1):    stage A0(T+2)->P     [A0 dead after P1]
//   P3(reads A1):    stage B1(T+2)->P     [B1 dead after P2]
//   P4(re-reads B0): stage A1(T+2)->P ; s_waitcnt vmcnt(6)
// vmcnt(6) confirms exactly tile T+1's 8 loads, leaves T+2's 6 in flight
// (m201's steady-state invariant). Drains to 0 only at T=NKT-2.
// ============================================================================
__global__ __launch_bounds__(512, 2) void lstm_gemm(
    const __bf16* __restrict__ A, const __bf16* __restrict__ Bt,
    const float* __restrict__ bx, const float* __restrict__ cin,
    float* __restrict__ out) {
    __shared__ __bf16 lds[2][32768];   // 128 KiB

    const int tid = threadIdx.x;
    const int lane = tid & 63;
    const int wid = tid >> 6;
    const int wm = wid >> 2;           // 0..1
    const int wn = wid & 3;            // 0..3
    const int lm = lane & 15, lu = lane >> 4;

    // XCD swizzle: XCD x owns M-panels [4x..4x+3] (4MB A, L2-resident window)
    // and streams all 16 N-panels (Bt 16MB deduped in LLC across XCDs).
    const int b = blockIdx.x;
    const int xcd = b & 7, cc = b >> 3;     // cc 0..63
    const int bxc = xcd * 4 + (cc >> 4);    // 0..31  (M/256)
    const int by  = cc & 15;                // 0..15  (N'/256)
    const int bm0 = bxc * 256;
    const int nb0 = by * 256;

    // ---- staging base pointers (per thread) ----
    const int lr = tid >> 3;           // 0..63 (row in round 0)
    const int ch = tid & 7;
    const __bf16* pA = A + (size_t)(bm0 + lr) * K_DIM + ch * 8;
    const __bf16* pB = Bt + (size_t)(nb0 + ((lr >> 5) << 6) + (lr & 31)) * K_DIM + ch * 8;
    // A region qm: +qm*131072 elem (=64 rows); round1: +262144 (=128 rows)
    // B region qn: +qn*65536  elem (=32 rows); round1: +262144

#define STAGE_A(P, QM, KT) do { \
    async_copy16(&lds[P][((QM) << 13) + tid * 8],        pA + (QM) * 131072 + (KT) * 64); \
    async_copy16(&lds[P][((QM) << 13) + 4096 + tid * 8], pA + (QM) * 131072 + 262144 + (KT) * 64); \
} while (0)
#define STAGE_B(P, QN, KT) do { \
    async_copy16(&lds[P][16384 + ((QN) << 13) + tid * 8],        pB + (QN) * 65536 + (KT) * 64); \
    async_copy16(&lds[P][16384 + ((QN) << 13) + 4096 + tid * 8], pB + (QN) * 65536 + 262144 + (KT) * 64); \
} while (0)

    // ---- prologue: tile 0 fully (8 loads), then tile 1's A0,B1,A1 (6) ----
    STAGE_A(0, 0, 0); STAGE_A(0, 1, 0); STAGE_B(0, 0, 0); STAGE_B(0, 1, 0);
    __builtin_amdgcn_sched_barrier(0);
    STAGE_A(1, 0, 1); STAGE_B(1, 1, 1); STAGE_A(1, 1, 1);
    __builtin_amdgcn_sched_barrier(0);

    // swizzled k-chunk byte offsets for ds_read_b128 (row parity = lm&7)
    const int jo0 = ((0 + lu) ^ (lm & 7)) * 8;   // kk=0, elements
    const int jo1 = ((4 + lu) ^ (lm & 7)) * 8;   // kk=1

    f32x4 acc[2][2][4][2];
    #pragma unroll
    for (int i0 = 0; i0 < 2; ++i0)
        #pragma unroll
        for (int k0_ = 0; k0_ < 2; ++k0_)
            #pragma unroll
            for (int m0 = 0; m0 < 4; ++m0)
                #pragma unroll
                for (int n0_ = 0; n0_ < 2; ++n0_)
                    acc[i0][k0_][m0][n0_] = f32x4{0.f, 0.f, 0.f, 0.f};

    bf16x8 a_[4][2];
    bf16x8 b_[2][2];

    asm volatile("s_waitcnt vmcnt(6)" ::: "memory");   // tile 0 resident
    __builtin_amdgcn_s_barrier();

#define READ_A(P, QM) do { \
    _Pragma("unroll") \
    for (int m_ = 0; m_ < 4; ++m_) { \
        const __bf16* ba_ = &lds[P][((QM) << 13) + (wm * 64 + m_ * 16 + lm) * 64]; \
        a_[m_][0] = *(const bf16x8*)(ba_ + jo0); \
        a_[m_][1] = *(const bf16x8*)(ba_ + jo1); \
    } \
} while (0)
#define READ_B(P, QN) do { \
    _Pragma("unroll") \
    for (int n_ = 0; n_ < 2; ++n_) { \
        const __bf16* bb_ = &lds[P][16384 + ((QN) << 13) + (wn * 32 + n_ * 16 + lm) * 64]; \
        b_[n_][0] = *(const bf16x8*)(bb_ + jo0); \
        b_[n_][1] = *(const bf16x8*)(bb_ + jo1); \
    } \
} while (0)
#define MFMA_PH(QM, QN) \
    _Pragma("unroll") \
    for (int m_ = 0; m_ < 4; ++m_) { \
        _Pragma("unroll") \
        for (int n_ = 0; n_ < 2; ++n_) { \
            acc[QM][QN][m_][n_] = __builtin_amdgcn_mfma_f32_16x16x32_bf16( \
                a_[m_][0], b_[n_][0], acc[QM][QN][m_][n_], 0, 0, 0); \
            acc[QM][QN][m_][n_] = __builtin_amdgcn_mfma_f32_16x16x32_bf16( \
                a_[m_][1], b_[n_][1], acc[QM][QN][m_][n_], 0, 0, 0); \
        } \
    }
#define PH_SYNC_PRE() \
    __builtin_amdgcn_sched_barrier(0); \
    __builtin_amdgcn_s_barrier(); \
    asm volatile("s_waitcnt lgkmcnt(0)" ::: "memory"); \
    __builtin_amdgcn_sched_barrier(0); \
    __builtin_amdgcn_s_setprio(1)
#define PH_SYNC_POST() \
    __builtin_amdgcn_s_setprio(0); \
    __builtin_amdgcn_sched_barrier(0); \
    __builtin_amdgcn_s_barrier()

#define GROUP(P, T) do { \
    /* P1 quadrant (0,0): reads A0 (8) + B0 (4); stage B0(T+1)->P^1 */ \
    READ_A(P, 0); READ_B(P, 0); \
    if ((T) + 1 < NKT) STAGE_B((P) ^ 1, 0, (T) + 1); \
    asm volatile("s_waitcnt lgkmcnt(8)" ::: "memory"); \
    PH_SYNC_PRE(); MFMA_PH(0, 0); PH_SYNC_POST(); \
    /* P2 quadrant (0,1): reads B1 (4); stage A0(T+2)->P */ \
    READ_B(P, 1); \
    if ((T) + 2 < NKT) STAGE_A(P, 0, (T) + 2); \
    PH_SYNC_PRE(); MFMA_PH(0, 1); PH_SYNC_POST(); \
    /* P3 quadrant (1,1): reads A1 (8); stage B1(T+2)->P */ \
    READ_A(P, 1); \
    if ((T) + 2 < NKT) STAGE_B(P, 1, (T) + 2); \
    PH_SYNC_PRE(); MFMA_PH(1, 1); PH_SYNC_POST(); \
    /* P4 quadrant (1,0): re-reads B0 (4); stage A1(T+2)->P; counted vmcnt */ \
    READ_B(P, 0); \
    if ((T) + 2 < NKT) STAGE_A(P, 1, (T) + 2); \
    if ((T) < NKT - 2) asm volatile("s_waitcnt vmcnt(6)" ::: "memory"); \
    else               asm volatile("s_waitcnt vmcnt(0)" ::: "memory"); \
    PH_SYNC_PRE(); MFMA_PH(1, 0); PH_SYNC_POST(); \
} while (0)

    #pragma unroll 1
    for (int it = 0; it < NKT / 2; ++it) {
        GROUP(0, 2 * it);
        GROUP(1, 2 * it + 1);
    }

    // ---- LSTM epilogue: gate = qn*2+nf is lane-local ----
    const int j = (by * 4 + wn) * 16 + lm;
    const float bi  = bx[j];
    const float bff = bx[H_DIM + j];
    const float bg  = bx[2 * H_DIM + j];
    const float bo  = bx[3 * H_DIM + j];
    #pragma unroll
    for (int qm = 0; qm < 2; ++qm) {
        #pragma unroll
        for (int m = 0; m < 4; ++m) {
            const int row0 = bm0 + wm * 128 + qm * 64 + m * 16 + lu * 4;
            #pragma unroll
            for (int r = 0; r < 4; ++r) {
                const size_t off = (size_t)(row0 + r) * H_DIM + j;
                const float iv = fast_sigmoid(acc[qm][0][m][0][r] + bi);
                const float fv = fast_sigmoid(acc[qm][0][m][1][r] + bff);
                const float gv = fast_tanh(acc[qm][1][m][0][r] + bg);
                const float ov = fast_sigmoid(acc[qm][1][m][1][r] + bo);
                const float cn = fv * cin[off] + iv * gv;
                out[off] = ov * fast_tanh(cn);
                out[(size_t)M_DIM * H_DIM + off] = cn;
            }
        }
    }
#undef STAGE_A
#undef STAGE_B
#undef READ_A
#undef READ_B
#undef MFMA_PH
#undef PH_SYNC_PRE
#undef PH_SYNC_POST
#undef GROUP
}

extern "C" void kernel_launch(void* const* d_in, const int* in_sizes, int n_in,
                              void* d_out, int out_size, void* d_ws, size_t ws_size,
                              hipStream_t stream) {
    const float* x  = (const float*)d_in[0];
    const float* h  = (const float*)d_in[1];
    const float* c  = (const float*)d_in[2];
    const float* Wx = (const float*)d_in[3];
    const float* bx = (const float*)d_in[4];
    const float* Wh = (const float*)d_in[5];
    float* out = (float*)d_out;

    __bf16* A  = (__bf16*)d_ws;                                      // 32 MB
    __bf16* Bt = (__bf16*)((char*)d_ws + (size_t)M_DIM * K_DIM * 2); // 16 MB

    pack_ab<<<4096, 256, 0, stream>>>(x, h, Wx, Wh, A, Bt);
    lstm_gemm<<<512, 512, 0, stream>>>(A, Bt, bx, c, out);
}

// Round 3
// 286.935 us; speedup vs baseline: 1.0455x; 1.0149x over previous
//
#include <hip/hip_runtime.h>
#include <hip/hip_bf16.h>
#include <cstdint>

typedef __bf16 bf16x8 __attribute__((ext_vector_type(8)));
typedef float f32x4 __attribute__((ext_vector_type(4)));

#define M_DIM 8192
#define H_DIM 1024
#define K_DIM 2048
#define NKT 32   // K tiles of 64

__device__ __forceinline__ void async_copy16(void* lds, const void* g) {
    __builtin_amdgcn_global_load_lds(
        (const __attribute__((address_space(1))) uint32_t*)g,
        (__attribute__((address_space(3))) uint32_t*)lds, 16, 0, 0);
}

__device__ __forceinline__ float fast_sigmoid(float x) {
    return __builtin_amdgcn_rcpf(1.0f + __expf(-x));
}
__device__ __forceinline__ float fast_tanh(float x) {
    float t = __expf(-2.0f * x);
    return (1.0f - t) * __builtin_amdgcn_rcpf(1.0f + t);
}

// ---- merged pack kernel: blocks [0,2048) pack A, [2048,4096) pack Bt ----
// A = bf16([x|h]) row-major [8192][2048], 16B-chunk c of row r stored at
// chunk pos (c&~7)|((c&7)^(r&7)).
// Bt[n'][k] = bf16(W^T), gate-interleaved rows: global gate col n_g=g*1024+j
// -> row n' = (j>>4)*64 + g*16 + (j&15); same chunk swizzle (n'&7 == j&7).
__global__ __launch_bounds__(256) void pack_ab(
    const float* __restrict__ x, const float* __restrict__ h,
    const float* __restrict__ Wx, const float* __restrict__ Wh,
    __bf16* __restrict__ A, __bf16* __restrict__ Bt) {
    __shared__ float tile[64 * 65];
    const int t = threadIdx.x;
    if (blockIdx.x < 2048) {
        const int ab = blockIdx.x;          // 4 batch rows per block
        #pragma unroll
        for (int i = 0; i < 4; ++i) {
            int p = t + i * 256;            // 0..1023
            int row = ab * 4 + (p >> 8);
            int c = p & 255;
            int col = c * 8;
            const float* src = (col < 1024) ? x + (size_t)row * 1024 + col
                                            : h + (size_t)row * 1024 + (col - 1024);
            float4 v0 = ((const float4*)src)[0];
            float4 v1 = ((const float4*)src)[1];
            union { __bf16 bb[8]; uint4 u; } pk;
            pk.bb[0] = (__bf16)v0.x; pk.bb[1] = (__bf16)v0.y;
            pk.bb[2] = (__bf16)v0.z; pk.bb[3] = (__bf16)v0.w;
            pk.bb[4] = (__bf16)v1.x; pk.bb[5] = (__bf16)v1.y;
            pk.bb[6] = (__bf16)v1.z; pk.bb[7] = (__bf16)v1.w;
            int sw = (c & ~7) | ((c & 7) ^ (row & 7));
            *(uint4*)(A + (size_t)row * K_DIM + sw * 8) = pk.u;
        }
    } else {
        const int b = blockIdx.x - 2048;
        const int bn = b & 63;
        const int bk = b >> 6;
        const int n0 = bn * 64, k0 = bk * 64;
        const float* W = (k0 < 1024) ? Wx + (size_t)k0 * 4096
                                     : Wh + (size_t)(k0 - 1024) * 4096;
        #pragma unroll
        for (int i = 0; i < 4; ++i) {
            int p = t + i * 256;
            int kr = p >> 4, c4 = p & 15;
            float4 v = *(const float4*)(W + (size_t)kr * 4096 + n0 + c4 * 4);
            float* dst = tile + kr * 65 + c4 * 4;
            dst[0] = v.x; dst[1] = v.y; dst[2] = v.z; dst[3] = v.w;
        }
        __syncthreads();
        #pragma unroll
        for (int i = 0; i < 2; ++i) {
            int p = t + i * 256;
            int n = p >> 3, ch = p & 7;
            int ng = n0 + n;                       // global gate-column 0..4095
            union { __bf16 bb[8]; uint4 u; } pk;
            #pragma unroll
            for (int j2 = 0; j2 < 8; ++j2)
                pk.bb[j2] = (__bf16)tile[(ch * 8 + j2) * 65 + n];
            int g = ng >> 10;
            int j = ng & 1023;
            int np = ((j >> 4) << 6) | (g << 4) | (j & 15);   // interleaved row
            int c = (k0 >> 3) + ch;
            int sw = (c & ~7) | ((c & 7) ^ (np & 7));
            *(uint4*)(Bt + (size_t)np * K_DIM + sw * 8) = pk.u;
        }
    }
}

// ============================================================================
// 256x256 tile, BK=64, 8 waves (2Mx4N). (M-half x K-half) phase split, 24
// ds_read_b128/K-tile/wave, double-buffered fragment regs (ax/ay, b0/b1) so
// each phase's reads issue ahead of the previous phase's MFMA cluster.
// ONLY 2 barriers per K-tile (derived from WAR deadness):
//   end-P3: A-mh0 of buf P fully read (kk0@P1, kk1@P3) -> S4 may overwrite.
//   end-P4: data-arrival fence for tile T+1 (after per-wave vmcnt(2)) and
//           frees A-mh1/B for next tile's stages.
// Stage units (2 loads each): S1 A-mh1(T+1)->P^1, S2 B-h0(T+1)->P^1,
// S3 B-h1(T+1)->P^1, S4 A-mh0(T+2)->P (after end-P3 barrier).
// vmcnt(2) once per K-tile at P4 confirms all of tile T+1, leaves S4 in
// flight. Drains to 0 only at T=NKT-2. Steady loop is branch-free (tail
// peeled). setprio(1) brackets each 16-MFMA cluster (waves drift between
// barriers -> role split exists).
// ============================================================================
__global__ __launch_bounds__(512, 2) void lstm_gemm(
    const __bf16* __restrict__ A, const __bf16* __restrict__ Bt,
    const float* __restrict__ bx, const float* __restrict__ cin,
    float* __restrict__ out) {
    __shared__ __bf16 lds[2][32768];   // 128 KiB

    const int tid = threadIdx.x;
    const int lane = tid & 63;
    const int wid = tid >> 6;
    const int wm = wid >> 2;           // 0..1  (M-wave)
    const int wn = wid & 3;            // 0..3  (N-wave)
    const int lm = lane & 15, lu = lane >> 4;

    // XCD swizzle: XCD x owns M-panels [4x..4x+3] (A window L2-resident),
    // streams the 16 N-panels (Bt deduped in LLC). FETCH 287->164MB in r2.
    const int b = blockIdx.x;
    const int xcd = b & 7, cc = b >> 3;     // cc 0..63
    const int bxc = xcd * 4 + (cc >> 4);    // 0..31  (M/256)
    const int by  = cc & 15;                // 0..15  (N'/256)
    const int bm0 = bxc * 256;
    const int nb0 = by * 256;

    // ---- staging base pointers (per thread) ----
    const int lr = tid >> 3;           // 0..63
    const int ch = tid & 7;
    const __bf16* pA = A + (size_t)(bm0 + lr) * K_DIM + ch * 8;
    const __bf16* pB = Bt + (size_t)(nb0 + ((lr >> 5) << 6) + (lr & 31)) * K_DIM + ch * 8;

#define STAGE_A(P, QM, KT) do { \
    async_copy16(&lds[P][((QM) << 13) + tid * 8],        pA + (QM) * 131072 + (KT) * 64); \
    async_copy16(&lds[P][((QM) << 13) + 4096 + tid * 8], pA + (QM) * 131072 + 262144 + (KT) * 64); \
} while (0)
#define STAGE_B(P, QN, KT) do { \
    async_copy16(&lds[P][16384 + ((QN) << 13) + tid * 8],        pB + (QN) * 65536 + (KT) * 64); \
    async_copy16(&lds[P][16384 + ((QN) << 13) + 4096 + tid * 8], pB + (QN) * 65536 + 262144 + (KT) * 64); \
} while (0)

    // ---- prologue: tile 0 complete (8 loads) + tile 1's A-mh0 (2) ----
    STAGE_A(0, 0, 0); STAGE_A(0, 1, 0); STAGE_B(0, 0, 0); STAGE_B(0, 1, 0);
    __builtin_amdgcn_sched_barrier(0);
    STAGE_A(1, 0, 1);
    __builtin_amdgcn_sched_barrier(0);
    asm volatile("s_waitcnt vmcnt(2)" ::: "memory");   // tile 0 resident
    __builtin_amdgcn_s_barrier();                      // all waves confirmed

    // swizzled k-chunk element offsets (row parity = lm&7)
    const int jo0 = ((0 + lu) ^ (lm & 7)) * 8;   // kk=0
    const int jo1 = ((4 + lu) ^ (lm & 7)) * 8;   // kk=1

    f32x4 acc[8][4];
    #pragma unroll
    for (int m0 = 0; m0 < 8; ++m0)
        #pragma unroll
        for (int n0 = 0; n0 < 4; ++n0)
            acc[m0][n0] = f32x4{0.f, 0.f, 0.f, 0.f};

    bf16x8 ax[4], ay[4], b0[4], b1[4];

#define RD_A(P, MH, JO, DST) do { \
    _Pragma("unroll") \
    for (int m_ = 0; m_ < 4; ++m_) \
        DST[m_] = *(const bf16x8*)(&lds[P][((MH) << 13) + (wm * 64 + m_ * 16 + lm) * 64] + (JO)); \
} while (0)
#define RD_B(P, JO, DST) do { \
    _Pragma("unroll") \
    for (int n_ = 0; n_ < 4; ++n_) \
        DST[n_] = *(const bf16x8*)(&lds[P][16384 + ((n_ >> 1) << 13) + (wn * 32 + (n_ & 1) * 16 + lm) * 64] + (JO)); \
} while (0)
#define MM(MH, AR, BR) do { \
    __builtin_amdgcn_s_setprio(1); \
    __builtin_amdgcn_sched_barrier(0); \
    _Pragma("unroll") \
    for (int m_ = 0; m_ < 4; ++m_) \
        _Pragma("unroll") \
        for (int n_ = 0; n_ < 4; ++n_) \
            acc[(MH) * 4 + m_][n_] = __builtin_amdgcn_mfma_f32_16x16x32_bf16( \
                AR[m_], BR[n_], acc[(MH) * 4 + m_][n_], 0, 0, 0); \
    __builtin_amdgcn_sched_barrier(0); \
    __builtin_amdgcn_s_setprio(0); \
} while (0)

// S123/S4: compile-time stage enables; VMN: 2 (steady), 0 (drain), -1 (none)
#define GROUP(P, T, S123, S4, VMN) do { \
    /* reads for P1 (mh0,kk0) + P2's A (mh1,kk0) + B(kk0): 12 reads */ \
    RD_A(P, 0, jo0, ax); RD_A(P, 1, jo0, ay); RD_B(P, jo0, b0); \
    if (S123) STAGE_A((P) ^ 1, 1, (T) + 1); \
    MM(0, ax, b0); \
    /* reads for P3 (mh0,kk1) + B(kk1): 8 reads */ \
    RD_A(P, 0, jo1, ax); RD_B(P, jo1, b1); \
    if (S123) STAGE_B((P) ^ 1, 0, (T) + 1); \
    MM(1, ay, b0); \
    /* reads for P4 (mh1,kk1): 4 reads */ \
    RD_A(P, 1, jo1, ay); \
    if (S123) STAGE_B((P) ^ 1, 1, (T) + 1); \
    MM(0, ax, b1); \
    __builtin_amdgcn_sched_barrier(0); \
    __builtin_amdgcn_s_barrier();              /* end-P3: A-mh0(P) dead */ \
    if (S4) STAGE_A(P, 0, (T) + 2); \
    if ((VMN) == 2)      asm volatile("s_waitcnt vmcnt(2)" ::: "memory"); \
    else if ((VMN) == 0) asm volatile("s_waitcnt vmcnt(0)" ::: "memory"); \
    MM(1, ay, b1); \
    __builtin_amdgcn_sched_barrier(0); \
    __builtin_amdgcn_s_barrier();              /* end-P4: arrival fence */ \
} while (0)

    #pragma unroll 1
    for (int it = 0; it < 15; ++it) {
        GROUP(0, 2 * it,     true, true, 2);
        GROUP(1, 2 * it + 1, true, true, 2);
    }
    GROUP(0, 30, true,  false, 0);
    GROUP(1, 31, false, false, -1);

    // ---- LSTM epilogue: gate = n is lane-local ----
    const int j = (by * 4 + wn) * 16 + lm;
    const float bi  = bx[j];
    const float bff = bx[H_DIM + j];
    const float bg  = bx[2 * H_DIM + j];
    const float bo  = bx[3 * H_DIM + j];
    #pragma unroll
    for (int mf = 0; mf < 8; ++mf) {
        const int row0 = bm0 + wm * 128 + (mf >> 2) * 64 + (mf & 3) * 16 + lu * 4;
        #pragma unroll
        for (int r = 0; r < 4; ++r) {
            const size_t off = (size_t)(row0 + r) * H_DIM + j;
            const float iv = fast_sigmoid(acc[mf][0][r] + bi);
            const float fv = fast_sigmoid(acc[mf][1][r] + bff);
            const float gv = fast_tanh(acc[mf][2][r] + bg);
            const float ov = fast_sigmoid(acc[mf][3][r] + bo);
            const float cn = fv * cin[off] + iv * gv;
            out[off] = ov * fast_tanh(cn);
            out[(size_t)M_DIM * H_DIM + off] = cn;
        }
    }
#undef STAGE_A
#undef STAGE_B
#undef RD_A
#undef RD_B
#undef MM
#undef GROUP
}

extern "C" void kernel_launch(void* const* d_in, const int* in_sizes, int n_in,
                              void* d_out, int out_size, void* d_ws, size_t ws_size,
                              hipStream_t stream) {
    const float* x  = (const float*)d_in[0];
    const float* h  = (const float*)d_in[1];
    const float* c  = (const float*)d_in[2];
    const float* Wx = (const float*)d_in[3];
    const float* bx = (const float*)d_in[4];
    const float* Wh = (const float*)d_in[5];
    float* out = (float*)d_out;

    __bf16* A  = (__bf16*)d_ws;                                      // 32 MB
    __bf16* Bt = (__bf16*)((char*)d_ws + (size_t)M_DIM * K_DIM * 2); // 16 MB

    pack_ab<<<4096, 256, 0, stream>>>(x, h, Wx, Wh, A, Bt);
    lstm_gemm<<<512, 512, 0, stream>>>(A, Bt, bx, c, out);
}